// Round 1
// baseline (368.082 us; speedup 1.0000x reference)
//
#include <hip/hip_runtime.h>
#include <math.h>

#define L_SEQ 512
#define BSZ 2
#define NH 8
#define HD 32
#define E 256

// ---------------- Kernel 1: in-projection ----------------
// qkv = query @ W^T + b ; scatter into head-major q/k/v: (B*H, L, D)
__global__ void inproj_kernel(const float* __restrict__ query,
                              const float* __restrict__ W,
                              const float* __restrict__ bias,
                              float* __restrict__ qh,
                              float* __restrict__ kh,
                              float* __restrict__ vh) {
    int row = blockIdx.x;            // 0..1023 = l*B + b
    int l = row >> 1, b = row & 1;
    int t = threadIdx.x;             // 0..255 = e (output col within part)
    __shared__ float xs[E];
    xs[t] = query[row * E + t];
    __syncthreads();

    int h = t >> 5, d = t & 31;
    size_t dst = ((size_t)(b * NH + h) * L_SEQ + l) * HD + d;
    const float4* xp = (const float4*)xs;

    float* outs[3] = {qh, kh, vh};
#pragma unroll
    for (int p = 0; p < 3; ++p) {
        const float4* wp = (const float4*)(W + (size_t)(p * E + t) * E);
        float a = 0.f;
#pragma unroll 8
        for (int i = 0; i < E / 4; ++i) {
            float4 w = wp[i], x = xp[i];
            a += w.x * x.x + w.y * x.y + w.z * x.z + w.w * x.w;
        }
        outs[p][dst] = a + bias[p * E + t];
    }
}

// ---------------- Kernel 2: fused scores + softmax + PV ----------------
// One block per (n, l), n = b*H + h. 512 threads, one per key m.
__global__ void attn_kernel(const float* __restrict__ qh,
                            const float* __restrict__ kh,
                            const float* __restrict__ vh,
                            const float* __restrict__ rpe,
                            const float* __restrict__ mask,
                            float* __restrict__ attn_out,
                            float* __restrict__ oh) {
    int bid = blockIdx.x;            // n*512 + l
    int l = bid & (L_SEQ - 1);
    int n = bid >> 9;
    int b = n >> 3, h = n & 7;
    int m = threadIdx.x;             // 0..511

    __shared__ float qs[HD];
    __shared__ float redmax[8];
    __shared__ float redsum[8];
    __shared__ float pl[L_SEQ];
    __shared__ float redv[16][HD];

    if (m < HD) qs[m] = qh[((size_t)n * L_SEQ + l) * HD + m];
    __syncthreads();

    const float4* kp = (const float4*)(kh + ((size_t)n * L_SEQ + m) * HD);
    const float4* rp = (const float4*)(rpe + (((size_t)b * L_SEQ + l) * L_SEQ + m) * E + h * HD);
    const float4* qp = (const float4*)qs;

    float aqk = 0.f, arel = 0.f;
#pragma unroll
    for (int i = 0; i < HD / 4; ++i) {
        float4 kv = kp[i], rv = rp[i], qv = qp[i];
        aqk  += kv.x * qv.x + kv.y * qv.y + kv.z * qv.z + kv.w * qv.w;
        arel += rv.x * qv.x + rv.y * qv.y + rv.z * qv.z + rv.w * qv.w;
    }
    float s = aqk * 0.17677669529663687f + arel + mask[l * L_SEQ + m];

    // ---- block softmax over 512 values (8 waves) ----
    int lane = m & 63, wid = m >> 6;
    float mx = s;
#pragma unroll
    for (int off = 32; off > 0; off >>= 1) mx = fmaxf(mx, __shfl_xor(mx, off));
    if (lane == 0) redmax[wid] = mx;
    __syncthreads();
    float bmax = redmax[0];
#pragma unroll
    for (int i = 1; i < 8; ++i) bmax = fmaxf(bmax, redmax[i]);

    float p = __expf(s - bmax);
    float sm = p;
#pragma unroll
    for (int off = 32; off > 0; off >>= 1) sm += __shfl_xor(sm, off);
    if (lane == 0) redsum[wid] = sm;
    __syncthreads();
    float bsum = 0.f;
#pragma unroll
    for (int i = 0; i < 8; ++i) bsum += redsum[i];

    float pn = p / bsum;
    attn_out[((size_t)n * L_SEQ + l) * L_SEQ + m] = pn;
    pl[m] = pn;
    __syncthreads();

    // ---- PV: out[d] = sum_m pn[m] * v[m,d] ----
    int d = m & 31;
    int g = m >> 5;                  // 0..15, each group handles 32 m's
    float acc = 0.f;
    int m0 = g * 32;
#pragma unroll 8
    for (int j = 0; j < 32; ++j) {
        acc += pl[m0 + j] * vh[((size_t)n * L_SEQ + m0 + j) * HD + d];
    }
    redv[g][d] = acc;
    __syncthreads();
    if (m < HD) {
        float ssum = 0.f;
#pragma unroll
        for (int gg = 0; gg < 16; ++gg) ssum += redv[gg][m];
        oh[((size_t)n * L_SEQ + l) * HD + m] = ssum;
    }
}

// ---------------- Kernel 3: out-projection ----------------
__global__ void outproj_kernel(const float* __restrict__ oh,
                               const float* __restrict__ W,
                               const float* __restrict__ bias,
                               float* __restrict__ out) {
    int row = blockIdx.x;            // l*B + b
    int l = row >> 1, b = row & 1;
    int t = threadIdx.x;             // output col 0..255
    __shared__ float xs[E];
    int h = t >> 5, d = t & 31;
    xs[t] = oh[((size_t)(b * NH + h) * L_SEQ + l) * HD + d];
    __syncthreads();

    const float4* wp = (const float4*)(W + (size_t)t * E);
    const float4* xp = (const float4*)xs;
    float a = 0.f;
#pragma unroll 8
    for (int i = 0; i < E / 4; ++i) {
        float4 w = wp[i], x = xp[i];
        a += w.x * x.x + w.y * x.y + w.z * x.z + w.w * x.w;
    }
    out[(size_t)row * E + t] = a + bias[t];
}

extern "C" void kernel_launch(void* const* d_in, const int* in_sizes, int n_in,
                              void* d_out, int out_size, void* d_ws, size_t ws_size,
                              hipStream_t stream) {
    const float* query = (const float*)d_in[0];
    // d_in[1] = key, d_in[2] = value -- UNUSED by the reference (it projects only query)
    const float* rpe   = (const float*)d_in[3];
    const float* mask  = (const float*)d_in[4];
    const float* Win   = (const float*)d_in[5];
    const float* bin   = (const float*)d_in[6];
    const float* Wout  = (const float*)d_in[7];
    const float* bout  = (const float*)d_in[8];

    float* out  = (float*)d_out;                       // (L,B,E) = 262144
    float* attn = (float*)d_out + (size_t)L_SEQ * BSZ * E;  // (B*H,L,L) = 4194304

    float* qh = (float*)d_ws;                          // (16,512,32) = 262144 floats
    float* kh = qh + (size_t)BSZ * NH * L_SEQ * HD;
    float* vh = kh + (size_t)BSZ * NH * L_SEQ * HD;
    float* oh = vh + (size_t)BSZ * NH * L_SEQ * HD;    // (16,512,32)

    inproj_kernel<<<L_SEQ * BSZ, E, 0, stream>>>(query, Win, bin, qh, kh, vh);
    attn_kernel<<<BSZ * NH * L_SEQ, L_SEQ, 0, stream>>>(qh, kh, vh, rpe, mask, attn, oh);
    outproj_kernel<<<L_SEQ * BSZ, E, 0, stream>>>(oh, Wout, bout, out);
}

// Round 2
// 193.040 us; speedup vs baseline: 1.9068x; 1.9068x over previous
//
#include <hip/hip_runtime.h>
#include <math.h>

#define L_SEQ 512
#define BSZ 2
#define NH 8
#define HD 32
#define E 256
#define SCALE 0.17677669529663687f

// ---------------- Kernel 1: in-projection ----------------
// qkv = query @ W^T + b ; scatter into head-major q/k/v: (B*H, L, D)
// 4 rows per block; 8 lanes cooperate per output column (coalesced W reads).
__global__ void inproj_kernel(const float* __restrict__ query,
                              const float* __restrict__ W,
                              const float* __restrict__ bias,
                              float* __restrict__ qh,
                              float* __restrict__ kh,
                              float* __restrict__ vh) {
    int r0 = blockIdx.x * 4;         // first of 4 rows (row = l*B + b)
    int t = threadIdx.x;             // 0..255
    __shared__ float xs[4][E];
#pragma unroll
    for (int r = 0; r < 4; ++r) xs[r][t] = query[(size_t)(r0 + r) * E + t];
    __syncthreads();

    int c  = t & 7;                  // k-chunk lane (8 lanes per column)
    int cg = t >> 3;                 // 0..31 column group
    float* outs[3] = {qh, kh, vh};

#pragma unroll
    for (int p = 0; p < 3; ++p) {
#pragma unroll
        for (int pass = 0; pass < 8; ++pass) {
            int col = pass * 32 + cg;                    // 0..255 within part
            const float4* wp = (const float4*)(W + (size_t)(p * E + col) * E);
            float a0 = 0.f, a1 = 0.f, a2 = 0.f, a3 = 0.f;
#pragma unroll
            for (int kk = 0; kk < 8; ++kk) {
                float4 w  = wp[c + kk * 8];              // lanes c=0..7 -> 128B contig
                float4 x0 = ((const float4*)xs[0])[c + kk * 8];
                float4 x1 = ((const float4*)xs[1])[c + kk * 8];
                float4 x2 = ((const float4*)xs[2])[c + kk * 8];
                float4 x3 = ((const float4*)xs[3])[c + kk * 8];
                a0 += w.x * x0.x + w.y * x0.y + w.z * x0.z + w.w * x0.w;
                a1 += w.x * x1.x + w.y * x1.y + w.z * x1.z + w.w * x1.w;
                a2 += w.x * x2.x + w.y * x2.y + w.z * x2.z + w.w * x2.w;
                a3 += w.x * x3.x + w.y * x3.y + w.z * x3.z + w.w * x3.w;
            }
#pragma unroll
            for (int off = 1; off <= 4; off <<= 1) {
                a0 += __shfl_xor(a0, off);
                a1 += __shfl_xor(a1, off);
                a2 += __shfl_xor(a2, off);
                a3 += __shfl_xor(a3, off);
            }
            if (c == 0) {
                int h = col >> 5, d = col & 31;
                float bb = bias[p * E + col];
                float res[4] = {a0, a1, a2, a3};
#pragma unroll
                for (int r = 0; r < 4; ++r) {
                    int row = r0 + r, l = row >> 1, b = row & 1;
                    outs[p][((size_t)(b * NH + h) * L_SEQ + l) * HD + d] = res[r] + bb;
                }
            }
        }
    }
}

// ---------------- Kernel 2: fused scores + softmax + PV ----------------
// One block per (n, l), n = b*H + h. 512 threads.
__global__ void attn_kernel(const float* __restrict__ qh,
                            const float* __restrict__ kh,
                            const float* __restrict__ vh,
                            const float* __restrict__ rpe,
                            const float* __restrict__ mask,
                            float* __restrict__ attn_out,
                            float* __restrict__ oh) {
    int bid = blockIdx.x;            // n*512 + l
    int l = bid & (L_SEQ - 1);
    int n = bid >> 9;
    int b = n >> 3, h = n & 7;
    int t = threadIdx.x;             // 0..511

    __shared__ float qs[HD];
    __shared__ float s_lds[L_SEQ];
    __shared__ float redmax[8];
    __shared__ float redsum[8];
    __shared__ float pl[L_SEQ];
    __shared__ float redv[16][HD];

    if (t < HD) qs[t] = qh[((size_t)n * L_SEQ + l) * HD + t];
    __syncthreads();

    // ---- Phase 1: scores. 8 lanes per key-row m; coalesced rpe/k reads. ----
    int c    = t & 7;                // chunk within row
    int mrow = t >> 3;               // 0..63
    float4 qc = ((const float4*)qs)[c];
    const float* kbase = kh + (size_t)n * L_SEQ * HD;
    const float* rbase = rpe + ((size_t)(b * L_SEQ + l) * L_SEQ) * E + h * HD;

#pragma unroll
    for (int mi = 0; mi < 8; ++mi) {
        int m = mi * 64 + mrow;
        float4 kv = *(const float4*)(kbase + (size_t)m * HD + c * 4);
        float4 rv = *(const float4*)(rbase + (size_t)m * E + c * 4);
        float part = (kv.x * qc.x + kv.y * qc.y + kv.z * qc.z + kv.w * qc.w) * SCALE
                   +  rv.x * qc.x + rv.y * qc.y + rv.z * qc.z + rv.w * qc.w;
        part += __shfl_xor(part, 1);
        part += __shfl_xor(part, 2);
        part += __shfl_xor(part, 4);
        if (c == 0) s_lds[m] = part;
    }
    __syncthreads();

    // ---- Phase 2: softmax over 512 values (8 waves) ----
    float s = s_lds[t] + mask[l * L_SEQ + t];
    int lane = t & 63, wid = t >> 6;
    float mx = s;
#pragma unroll
    for (int off = 32; off > 0; off >>= 1) mx = fmaxf(mx, __shfl_xor(mx, off));
    if (lane == 0) redmax[wid] = mx;
    __syncthreads();
    float bmax = redmax[0];
#pragma unroll
    for (int i = 1; i < 8; ++i) bmax = fmaxf(bmax, redmax[i]);

    float p = __expf(s - bmax);
    float sm = p;
#pragma unroll
    for (int off = 32; off > 0; off >>= 1) sm += __shfl_xor(sm, off);
    if (lane == 0) redsum[wid] = sm;
    __syncthreads();
    float bsum = 0.f;
#pragma unroll
    for (int i = 0; i < 8; ++i) bsum += redsum[i];

    float pn = p / bsum;
    attn_out[((size_t)n * L_SEQ + l) * L_SEQ + t] = pn;
    pl[t] = pn;
    __syncthreads();

    // ---- Phase 3: PV: out[d] = sum_m pn[m] * v[m,d] ----
    int d = t & 31;
    int g = t >> 5;                  // 0..15, each group handles 32 m's
    float acc = 0.f;
    int m0 = g * 32;
#pragma unroll 8
    for (int j = 0; j < 32; ++j) {
        acc += pl[m0 + j] * vh[((size_t)n * L_SEQ + m0 + j) * HD + d];
    }
    redv[g][d] = acc;
    __syncthreads();
    if (t < HD) {
        float ssum = 0.f;
#pragma unroll
        for (int gg = 0; gg < 16; ++gg) ssum += redv[gg][t];
        oh[((size_t)n * L_SEQ + l) * HD + t] = ssum;
    }
}

// ---------------- Kernel 3: out-projection ----------------
// 4 rows per block; 8 lanes per output column.
__global__ void outproj_kernel(const float* __restrict__ oh,
                               const float* __restrict__ W,
                               const float* __restrict__ bias,
                               float* __restrict__ out) {
    int r0 = blockIdx.x * 4;
    int t = threadIdx.x;             // 0..255
    __shared__ float xs[4][E];
#pragma unroll
    for (int r = 0; r < 4; ++r) {
        int row = r0 + r, l = row >> 1, b = row & 1;
        int h = t >> 5, d = t & 31;
        xs[r][t] = oh[((size_t)(b * NH + h) * L_SEQ + l) * HD + d];
    }
    __syncthreads();

    int c  = t & 7;
    int cg = t >> 3;
#pragma unroll
    for (int pass = 0; pass < 8; ++pass) {
        int col = pass * 32 + cg;
        const float4* wp = (const float4*)(W + (size_t)col * E);
        float a0 = 0.f, a1 = 0.f, a2 = 0.f, a3 = 0.f;
#pragma unroll
        for (int kk = 0; kk < 8; ++kk) {
            float4 w  = wp[c + kk * 8];
            float4 x0 = ((const float4*)xs[0])[c + kk * 8];
            float4 x1 = ((const float4*)xs[1])[c + kk * 8];
            float4 x2 = ((const float4*)xs[2])[c + kk * 8];
            float4 x3 = ((const float4*)xs[3])[c + kk * 8];
            a0 += w.x * x0.x + w.y * x0.y + w.z * x0.z + w.w * x0.w;
            a1 += w.x * x1.x + w.y * x1.y + w.z * x1.z + w.w * x1.w;
            a2 += w.x * x2.x + w.y * x2.y + w.z * x2.z + w.w * x2.w;
            a3 += w.x * x3.x + w.y * x3.y + w.z * x3.z + w.w * x3.w;
        }
#pragma unroll
        for (int off = 1; off <= 4; off <<= 1) {
            a0 += __shfl_xor(a0, off);
            a1 += __shfl_xor(a1, off);
            a2 += __shfl_xor(a2, off);
            a3 += __shfl_xor(a3, off);
        }
        if (c == 0) {
            float bb = bias[col];
            float res[4] = {a0, a1, a2, a3};
#pragma unroll
            for (int r = 0; r < 4; ++r) {
                out[(size_t)(r0 + r) * E + col] = res[r] + bb;
            }
        }
    }
}

extern "C" void kernel_launch(void* const* d_in, const int* in_sizes, int n_in,
                              void* d_out, int out_size, void* d_ws, size_t ws_size,
                              hipStream_t stream) {
    const float* query = (const float*)d_in[0];
    // d_in[1] = key, d_in[2] = value -- UNUSED by the reference (it projects only query)
    const float* rpe   = (const float*)d_in[3];
    const float* mask  = (const float*)d_in[4];
    const float* Win   = (const float*)d_in[5];
    const float* bin   = (const float*)d_in[6];
    const float* Wout  = (const float*)d_in[7];
    const float* bout  = (const float*)d_in[8];

    float* out  = (float*)d_out;                            // (L,B,E)
    float* attn = (float*)d_out + (size_t)L_SEQ * BSZ * E;  // (B*H,L,L)

    float* qh = (float*)d_ws;                               // (16,512,32)
    float* kh = qh + (size_t)BSZ * NH * L_SEQ * HD;
    float* vh = kh + (size_t)BSZ * NH * L_SEQ * HD;
    float* oh = vh + (size_t)BSZ * NH * L_SEQ * HD;

    inproj_kernel<<<(L_SEQ * BSZ) / 4, E, 0, stream>>>(query, Win, bin, qh, kh, vh);
    attn_kernel<<<BSZ * NH * L_SEQ, L_SEQ, 0, stream>>>(qh, kh, vh, rpe, mask, attn, oh);
    outproj_kernel<<<(L_SEQ * BSZ) / 4, E, 0, stream>>>(oh, Wout, bout, out);
}

// Round 4
// 165.090 us; speedup vs baseline: 2.2296x; 1.1693x over previous
//
#include <hip/hip_runtime.h>
#include <math.h>

#define L_SEQ 512
#define BSZ 2
#define NH 8
#define HD 32
#define E 256
#define SCALE 0.17677669529663687f

typedef float f32x4 __attribute__((ext_vector_type(4)));

// Workspace layouts:
//   q2, k2 : (B, L, E)      -- 1KB contiguous row per (b, seq), same shape as rpe rows
//   vh     : (B*NH, L, HD)  -- head-major, 1KB contiguous per 8 rows for PV
//   oh2    : (B, L, E)      -- contiguous row for out-projection

// ---------------- Kernel 1: in-projection ----------------
__global__ void inproj_kernel(const float* __restrict__ query,
                              const float* __restrict__ W,
                              const float* __restrict__ bias,
                              float* __restrict__ q2,
                              float* __restrict__ k2,
                              float* __restrict__ vh) {
    int r0 = blockIdx.x * 4;         // first of 4 rows (row = l*B + b)
    int t = threadIdx.x;             // 0..255
    __shared__ float xs[4][E];
#pragma unroll
    for (int r = 0; r < 4; ++r) xs[r][t] = query[(size_t)(r0 + r) * E + t];
    __syncthreads();

    int c  = t & 7;                  // 8 lanes cooperate per output column
    int cg = t >> 3;

#pragma unroll
    for (int p = 0; p < 3; ++p) {
#pragma unroll
        for (int pass = 0; pass < 8; ++pass) {
            int col = pass * 32 + cg;                    // 0..255 within part
            const float4* wp = (const float4*)(W + (size_t)(p * E + col) * E);
            float a0 = 0.f, a1 = 0.f, a2 = 0.f, a3 = 0.f;
#pragma unroll
            for (int kk = 0; kk < 8; ++kk) {
                float4 w  = wp[c + kk * 8];
                float4 x0 = ((const float4*)xs[0])[c + kk * 8];
                float4 x1 = ((const float4*)xs[1])[c + kk * 8];
                float4 x2 = ((const float4*)xs[2])[c + kk * 8];
                float4 x3 = ((const float4*)xs[3])[c + kk * 8];
                a0 += w.x * x0.x + w.y * x0.y + w.z * x0.z + w.w * x0.w;
                a1 += w.x * x1.x + w.y * x1.y + w.z * x1.z + w.w * x1.w;
                a2 += w.x * x2.x + w.y * x2.y + w.z * x2.z + w.w * x2.w;
                a3 += w.x * x3.x + w.y * x3.y + w.z * x3.z + w.w * x3.w;
            }
#pragma unroll
            for (int off = 1; off <= 4; off <<= 1) {
                a0 += __shfl_xor(a0, off);
                a1 += __shfl_xor(a1, off);
                a2 += __shfl_xor(a2, off);
                a3 += __shfl_xor(a3, off);
            }
            if (c == 0) {
                float bb = bias[p * E + col];
                float res[4] = {a0, a1, a2, a3};
#pragma unroll
                for (int r = 0; r < 4; ++r) {
                    int row = r0 + r, l = row >> 1, b = row & 1;
                    float val = res[r] + bb;
                    if (p == 0) {
                        q2[((size_t)b * L_SEQ + l) * E + col] = val;
                    } else if (p == 1) {
                        k2[((size_t)b * L_SEQ + l) * E + col] = val;
                    } else {
                        int h = col >> 5, d = col & 31;
                        vh[((size_t)(b * NH + h) * L_SEQ + l) * HD + d] = val;
                    }
                }
            }
        }
    }
}

// ---------------- Kernel 2: fused scores + softmax + PV ----------------
// One block per (b, l); all 8 heads. 512 threads = 8 waves; wave w owns head w
// for softmax + PV. Phase 1: each wave-instruction reads one full 1KB rpe row.
__global__ void attn_kernel(const float* __restrict__ q2,
                            const float* __restrict__ k2,
                            const float* __restrict__ vh,
                            const float* __restrict__ rpe,
                            const float* __restrict__ mask,
                            float* __restrict__ attn_out,
                            float* __restrict__ oh2) {
    int bid = blockIdx.x;            // b*512 + l
    int b = bid >> 9, l = bid & (L_SEQ - 1);
    int t = threadIdx.x;
    int lane = t & 63, wid = t >> 6;

    __shared__ float qs[E];
    __shared__ float s_lds[NH][L_SEQ + 1];   // pad: conflict-free scatter writes

    if (t < E) qs[t] = q2[((size_t)b * L_SEQ + l) * E + t];
    __syncthreads();

    // ---- Phase 1: scores for all heads. Wave w streams rows m = w*64..w*64+63.
    float4 qc = ((const float4*)qs)[lane];   // lane's head = lane>>3, dims (lane&7)*4..+3
    int h1 = lane >> 3;
    const float* kbase = k2 + (size_t)b * L_SEQ * E;
    const float* rbase = rpe + ((size_t)(b * L_SEQ + l)) * L_SEQ * E;

#pragma unroll 4
    for (int i = 0; i < 64; ++i) {
        int m = wid * 64 + i;
        float4 kv = ((const float4*)(kbase + (size_t)m * E))[lane];
        f32x4 rv = __builtin_nontemporal_load(((const f32x4*)(rbase + (size_t)m * E)) + lane);
        float part = (kv.x * qc.x + kv.y * qc.y + kv.z * qc.z + kv.w * qc.w) * SCALE
                   +  rv.x * qc.x + rv.y * qc.y + rv.z * qc.z + rv.w * qc.w;
        part += __shfl_xor(part, 1);
        part += __shfl_xor(part, 2);
        part += __shfl_xor(part, 4);
        if ((lane & 7) == 0) s_lds[h1][m] = part;
    }
    __syncthreads();

    // ---- Phase 2: softmax. Wave w owns head w (512 scores = 64 lanes x 8).
    int h = wid;
    const float* mrow = mask + (size_t)l * L_SEQ;
    float sv[8];
    float mx = -1e30f;
#pragma unroll
    for (int i = 0; i < 8; ++i) {
        int m = i * 64 + lane;
        sv[i] = s_lds[h][m] + mrow[m];
        mx = fmaxf(mx, sv[i]);
    }
#pragma unroll
    for (int off = 32; off > 0; off >>= 1) mx = fmaxf(mx, __shfl_xor(mx, off));
    float sum = 0.f;
#pragma unroll
    for (int i = 0; i < 8; ++i) { sv[i] = __expf(sv[i] - mx); sum += sv[i]; }
#pragma unroll
    for (int off = 32; off > 0; off >>= 1) sum += __shfl_xor(sum, off);
    float inv = 1.0f / sum;

    float* arow = attn_out + ((size_t)(b * NH + h) * L_SEQ + l) * L_SEQ;
#pragma unroll
    for (int i = 0; i < 8; ++i) {
        int m = i * 64 + lane;
        float pn = sv[i] * inv;
        arow[m] = pn;
        s_lds[h][m] = pn;       // wave-local: written and read by wave w only below
    }

    // ---- Phase 3: PV for head h (wave-local, no barrier needed).
    // lane = mg*8 + dq: mg = m-group (8 rows), dq = d-quad. 1KB contiguous v read/instr.
    int dq = lane & 7, mg = lane >> 3;
    const float4* vbase = (const float4*)(vh + (size_t)(b * NH + h) * L_SEQ * HD);
    float4 acc = {0.f, 0.f, 0.f, 0.f};
#pragma unroll 4
    for (int i = 0; i < 64; ++i) {
        int m = i * 8 + mg;
        float4 v4 = vbase[(size_t)m * 8 + dq];
        float p = s_lds[h][m];
        acc.x += p * v4.x; acc.y += p * v4.y; acc.z += p * v4.z; acc.w += p * v4.w;
    }
#pragma unroll
    for (int off = 8; off <= 32; off <<= 1) {
        acc.x += __shfl_xor(acc.x, off);
        acc.y += __shfl_xor(acc.y, off);
        acc.z += __shfl_xor(acc.z, off);
        acc.w += __shfl_xor(acc.w, off);
    }
    if (mg == 0) {
        ((float4*)(oh2 + ((size_t)b * L_SEQ + l) * E))[h * 8 + dq] = acc;
    }
}

// ---------------- Kernel 3: out-projection ----------------
__global__ void outproj_kernel(const float* __restrict__ oh2,
                               const float* __restrict__ W,
                               const float* __restrict__ bias,
                               float* __restrict__ out) {
    int r0 = blockIdx.x * 4;
    int t = threadIdx.x;             // 0..255
    __shared__ float xs[4][E];
#pragma unroll
    for (int r = 0; r < 4; ++r) {
        int row = r0 + r, l = row >> 1, b = row & 1;
        xs[r][t] = oh2[((size_t)b * L_SEQ + l) * E + t];
    }
    __syncthreads();

    int c  = t & 7;
    int cg = t >> 3;
#pragma unroll
    for (int pass = 0; pass < 8; ++pass) {
        int col = pass * 32 + cg;
        const float4* wp = (const float4*)(W + (size_t)col * E);
        float a0 = 0.f, a1 = 0.f, a2 = 0.f, a3 = 0.f;
#pragma unroll
        for (int kk = 0; kk < 8; ++kk) {
            float4 w  = wp[c + kk * 8];
            float4 x0 = ((const float4*)xs[0])[c + kk * 8];
            float4 x1 = ((const float4*)xs[1])[c + kk * 8];
            float4 x2 = ((const float4*)xs[2])[c + kk * 8];
            float4 x3 = ((const float4*)xs[3])[c + kk * 8];
            a0 += w.x * x0.x + w.y * x0.y + w.z * x0.z + w.w * x0.w;
            a1 += w.x * x1.x + w.y * x1.y + w.z * x1.z + w.w * x1.w;
            a2 += w.x * x2.x + w.y * x2.y + w.z * x2.z + w.w * x2.w;
            a3 += w.x * x3.x + w.y * x3.y + w.z * x3.z + w.w * x3.w;
        }
#pragma unroll
        for (int off = 1; off <= 4; off <<= 1) {
            a0 += __shfl_xor(a0, off);
            a1 += __shfl_xor(a1, off);
            a2 += __shfl_xor(a2, off);
            a3 += __shfl_xor(a3, off);
        }
        if (c == 0) {
            float bb = bias[col];
            float res[4] = {a0, a1, a2, a3};
#pragma unroll
            for (int r = 0; r < 4; ++r) {
                out[(size_t)(r0 + r) * E + col] = res[r] + bb;
            }
        }
    }
}

extern "C" void kernel_launch(void* const* d_in, const int* in_sizes, int n_in,
                              void* d_out, int out_size, void* d_ws, size_t ws_size,
                              hipStream_t stream) {
    const float* query = (const float*)d_in[0];
    // d_in[1] = key, d_in[2] = value -- UNUSED by the reference (it projects only query)
    const float* rpe   = (const float*)d_in[3];
    const float* mask  = (const float*)d_in[4];
    const float* Win   = (const float*)d_in[5];
    const float* bin   = (const float*)d_in[6];
    const float* Wout  = (const float*)d_in[7];
    const float* bout  = (const float*)d_in[8];

    float* out  = (float*)d_out;                            // (L,B,E)
    float* attn = (float*)d_out + (size_t)L_SEQ * BSZ * E;  // (B*H,L,L)

    float* q2  = (float*)d_ws;                              // (B,L,E)
    float* k2  = q2 + (size_t)BSZ * L_SEQ * E;              // (B,L,E)
    float* vh  = k2 + (size_t)BSZ * L_SEQ * E;              // (B*H,L,D)
    float* oh2 = vh + (size_t)BSZ * NH * L_SEQ * HD;        // (B,L,E)

    inproj_kernel<<<(L_SEQ * BSZ) / 4, E, 0, stream>>>(query, Win, bin, q2, k2, vh);
    attn_kernel<<<BSZ * L_SEQ, 512, 0, stream>>>(q2, k2, vh, rpe, mask, attn, oh2);
    outproj_kernel<<<(L_SEQ * BSZ) / 4, E, 0, stream>>>(oh2, Wout, bout, out);
}